// Round 8
// baseline (157.330 us; speedup 1.0000x reference)
//
#include <hip/hip_runtime.h>
#include <hip/hip_bf16.h>

// ---------------------------------------------------------------------------
// Binary CNN forward (eval):
//  conv3x3(sign(x), sign(W1)) + b1 -> maxpool2x2 -> BN -> hardtanh -> sign
//  -> (i8 MFMA GEMM vs sign(W2)) + b2 -> BN -> hardtanh
//  -> fused W3 projection (atomic partial sums) -> +b3, log_softmax
//
// All sign arithmetic is exact integer math (i8 dot products / i32 MFMA).
// mm_i8 (R8): A operand loaded DIRECTLY global->VGPR (dbuf register sets,
// 2 chunks ahead; L1 serves the 2x N-wave re-read). B via LDS double buffer
// (gld_lds, 1 ahead), counted vmcnt(8), one barrier per chunk. This removes
// the LDS-read-BW wall diagnosed in R7 (128 KB -> 64 KB reads per chunk/CU).
// ---------------------------------------------------------------------------

#define EPS 1e-5f

typedef int i32x4 __attribute__((ext_vector_type(4)));
typedef int i32x16 __attribute__((ext_vector_type(16)));

#define GLD_LDS(gsrc, ldst)                                                   \
  __builtin_amdgcn_global_load_lds(                                           \
      (const __attribute__((address_space(1))) void*)(gsrc),                  \
      (__attribute__((address_space(3))) void*)(ldst), 16, 0, 0)

// v_dot4_i32_i8: 4-way i8 dot + i32 acc in one instruction
#if defined(__has_builtin)
#if __has_builtin(__builtin_amdgcn_sdot4)
#define SDOT4(a, b, c) __builtin_amdgcn_sdot4((int)(a), (int)(b), (c), false)
#endif
#endif
#ifndef SDOT4
static __device__ __forceinline__ int sdot4_fb(int a, int b, int c) {
#pragma unroll
  for (int k = 0; k < 4; k++)
    c += ((int)(signed char)(a >> (8 * k))) * ((int)(signed char)(b >> (8 * k)));
  return c;
}
#define SDOT4(a, b, c) sdot4_fb((int)(a), (int)(b), (c))
#endif

// ---------- Stage 1 (merged): conv+pool+BN sign -> A8 | sign(W2) -> B8 ------
__global__ __launch_bounds__(256) void stage1(
    const float* __restrict__ x, const float* __restrict__ W1,
    const float* __restrict__ b1, const float* __restrict__ g1,
    const float* __restrict__ be1, const float* __restrict__ m1,
    const float* __restrict__ v1, const float* __restrict__ W2,
    signed char* __restrict__ A8, signed char* __restrict__ B8) {
  const int t = threadIdx.x;

  if (blockIdx.x >= 4096) {
    // ---- pack sign(W2) rows as int8 ----
    const int row = blockIdx.x - 4096;
    const float* wr = W2 + (long)row * 6272;
    signed char* br = B8 + (long)row * 6272;
    for (int it = 0; it < 25; it++) {
      int f = it * 256 + t;
      if (f < 6272) br[f] = (wr[f] >= 0.f) ? (signed char)1 : (signed char)-1;
    }
    return;
  }

  // ---- conv path ----
  __shared__ signed char sxb[30 * 32];  // padded binarized image, bytes
  __shared__ int wdw[32][3][2];         // weight dwords: [c][kh][dj]
  __shared__ float cAB[32][2];          // {cA, cB} per channel

  const int b = blockIdx.x;
  for (int i = t; i < 240; i += 256) ((int*)sxb)[i] = 0;  // zero incl. border
  __syncthreads();

  const float* xb = x + b * 784;
  for (int p = t; p < 784; p += 256) {
    float v = xb[p];
    sxb[(p / 28 + 1) * 32 + (p % 28) + 1] = (v >= 0.f) ? (signed char)1
                                                       : (signed char)-1;
  }
  if (t < 96) {
    int c = t / 3, kh = t - c * 3;
    const float* wp = W1 + c * 9 + kh * 3;
    unsigned u0 = (wp[0] >= 0.f) ? 0x01u : 0xFFu;
    unsigned u1 = (wp[1] >= 0.f) ? 0x01u : 0xFFu;
    unsigned u2 = (wp[2] >= 0.f) ? 0x01u : 0xFFu;
    wdw[c][kh][0] = (int)((u2 << 16) | (u1 << 8) | u0);   // (w0,w1,w2,0)
    wdw[c][kh][1] = (int)((u2 << 24) | (u1 << 16) | (u0 << 8));  // (0,w0,w1,w2)
  }
  if (t < 32) {
    float sc = g1[t] * rsqrtf(v1[t] + EPS);
    cAB[t][0] = sc;
    cAB[t][1] = sc * (b1[t] - m1[t]) + be1[t];  // pred = cA*maxconv + cB >= 0
  }
  __syncthreads();

  if (t < 196) {
    const int h = t / 14, w = t - h * 14;
    const int i0 = 2 * h, j0 = 2 * w;
    const int base = j0 & ~3, sh = (j0 & 3) * 8;  // sh in {0,16}
    unsigned prow[4];
#pragma unroll
    for (int ii = 0; ii < 4; ii++) {
      const int* rp = (const int*)&sxb[(i0 + ii) * 32 + base];
      unsigned long long chunk =
          (unsigned)rp[0] | ((unsigned long long)(unsigned)rp[1] << 32);
      prow[ii] = (unsigned)(chunk >> sh);  // bytes j0..j0+3 of padded row
    }
    signed char* ar = A8 + (long)b * 6272 + t;
#pragma unroll 8
    for (int c = 0; c < 32; c++) {
      int w00 = wdw[c][0][0], w01 = wdw[c][0][1];
      int w10 = wdw[c][1][0], w11 = wdw[c][1][1];
      int w20 = wdw[c][2][0], w21 = wdw[c][2][1];
      int c00 = SDOT4(prow[0], w00, SDOT4(prow[1], w10, SDOT4(prow[2], w20, 0)));
      int c01 = SDOT4(prow[0], w01, SDOT4(prow[1], w11, SDOT4(prow[2], w21, 0)));
      int c10 = SDOT4(prow[1], w00, SDOT4(prow[2], w10, SDOT4(prow[3], w20, 0)));
      int c11 = SDOT4(prow[1], w01, SDOT4(prow[2], w11, SDOT4(prow[3], w21, 0)));
      int mx = max(max(c00, c01), max(c10, c11));
      float pred = cAB[c][0] * (float)mx + cAB[c][1];
      ar[c * 196] = (pred >= 0.f) ? (signed char)1 : (signed char)-1;
    }
  }
}

// ---------- i8 MFMA GEMM 4096x2048 (K=6272) + BN2 + clip + W3 partials ------
// 256x128 tile, 512 threads (8 waves, 4M x 2N), wave tile 64x64 (2x2 of
// 32x32x32_i8). A: global->VGPR direct, double register set, 2 chunks ahead.
// B: LDS double buffer via gld_lds, 1 chunk ahead, counted vmcnt(8).
#define TM 256
#define TN 128
#define BKB 128        // K bytes per chunk
#define NKC 49         // 6272 / 128

// LDS map:
//  [0, 16384)       : B buffer 0 (128 rows x 128 B)
//  [16384, 32768)   : B buffer 1
//  [0, 67584)       : epilogue overlay zb[128][132] f32 (after main loop)
//  [67584, 72864)   : w3s[10][132] f32
__global__ __launch_bounds__(512, 2) void mm_i8(
    const signed char* __restrict__ A8, const signed char* __restrict__ B8,
    const float* __restrict__ b2, const float* __restrict__ g2,
    const float* __restrict__ be2, const float* __restrict__ m2,
    const float* __restrict__ v2, const float* __restrict__ W3,
    float* __restrict__ logits) {
  __shared__ __align__(16) char smem[72864];
  float* w3s = (float*)(smem + 67584);

  const int t = threadIdx.x;
  const int lane = t & 63, wv = t >> 6;
  const int l31 = lane & 31, lh = lane >> 5;
  const int wr = wv >> 1, wc = wv & 1;   // wave grid 4M x 2N

  // XCD-aware swizzle: 256 blocks = 1/CU; each XCD gets 32 consecutive swz
  // = 2 M-panels x 16 N-panels (A slice 3.2 MB < 4 MB XCD L2).
  const int bid = blockIdx.x;
  const int swz = (bid & 7) * 32 + (bid >> 3);
  const long tileM = (long)(swz >> 4) * TM;
  const long tileN = (long)(swz & 15) * TN;

  for (int i = t; i < 1320; i += 512) {
    int cls = i / 132, c = i - cls * 132;
    w3s[i] = (c < 128) ? W3[cls * 2048 + tileN + c] : 0.f;
  }

  // Stage B chunk kc into buffer (kc&1): 16 KB = 16 gld_lds, 2 per wave.
  // LDS linear slot sl holds global slot sl^(r&7); frag read re-applies XOR.
  auto stageB = [&](int kc) {
    const int kb = kc * BKB;
    char* base = smem + (kc & 1) * 16384;
#pragma unroll
    for (int j = 0; j < 2; j++) {
      int o = (wv * 2 + j) * 1024 + lane * 16;
      int r = o >> 7, sl = (o >> 4) & 7;
      GLD_LDS(B8 + (tileN + r) * 6272 + kb + ((sl ^ (r & 7)) << 4),
              base + (wv * 2 + j) * 1024);
    }
  };

  // Load A chunk kc for this wave directly into registers (8 x 16 B):
  // same bytes the proven LDS path delivered: row=wr*64+mt*32+l31,
  // bytes [kc*128 + slot*16, +16), slot = ks*2+lh.
  const signed char* aRow0 = A8 + (tileM + wr * 64 + l31) * 6272;
  const signed char* aRow1 = aRow0 + 32 * 6272;
  auto loadA = [&](i32x4 (&a)[8], int kc) {
    const int kb = kc * BKB;
#pragma unroll
    for (int ks = 0; ks < 4; ks++) {
      a[ks] = *(const i32x4*)(aRow0 + kb + (ks * 2 + lh) * 16);
      a[4 + ks] = *(const i32x4*)(aRow1 + kb + (ks * 2 + lh) * 16);
    }
  };

  i32x16 acc[2][2];
#pragma unroll
  for (int a = 0; a < 2; a++)
#pragma unroll
    for (int q = 0; q < 2; q++) acc[a][q] = (i32x16)0;

  i32x4 aEven[8], aOdd[8];
  stageB(0);
  loadA(aEven, 0);
  loadA(aOdd, 1);

  // One chunk: wait B(kc)+A(kc) [newest 8 outstanding = A(kc+1)], barrier,
  // stage B(kc+1), read B frags, MFMA, then load A(kc+2) into freed set.
  auto chunk = [&](int kc, i32x4 (&aset)[8]) {
    if (kc == NKC - 1)
      asm volatile("s_waitcnt vmcnt(0)" ::: "memory");
    else
      asm volatile("s_waitcnt vmcnt(8)" ::: "memory");
    __builtin_amdgcn_s_barrier();
    if (kc + 1 < NKC) stageB(kc + 1);

    const char* bbase = smem + (kc & 1) * 16384;
    i32x4 bf[2][4];
#pragma unroll
    for (int nt = 0; nt < 2; nt++) {
      int r = wc * 64 + nt * 32 + l31;
      const char* bp = bbase + r * 128;
#pragma unroll
      for (int ks = 0; ks < 4; ks++) {
        int slot = ks * 2 + lh;
        bf[nt][ks] = *(const i32x4*)(bp + ((slot ^ (r & 7)) << 4));
      }
    }
    __builtin_amdgcn_s_setprio(1);
#pragma unroll
    for (int ks = 0; ks < 4; ks++) {
#pragma unroll
      for (int mt = 0; mt < 2; mt++)
#pragma unroll
        for (int nt = 0; nt < 2; nt++)
          acc[mt][nt] = __builtin_amdgcn_mfma_i32_32x32x32_i8(
              aset[mt * 4 + ks], bf[nt][ks], acc[mt][nt], 0, 0, 0);
    }
    __builtin_amdgcn_s_setprio(0);
    if (kc + 2 < NKC) loadA(aset, kc + 2);  // overwrite freed parity set
  };

  for (int kc2 = 0; kc2 < NKC - 1; kc2 += 2) {  // 0..47 in pairs
    chunk(kc2, aEven);
    chunk(kc2 + 1, aOdd);
  }
  chunk(NKC - 1, aEven);  // kc=48 (even)

  __builtin_amdgcn_s_barrier();  // all B reads done; smem may be overlaid

  // ---- epilogue: two 128-row passes; z = clip(BN2(dot)) -> LDS -> W3 dots --
  float* zb = (float*)smem;  // [128][132] f32 = 67584 B
#pragma unroll
  for (int pass = 0; pass < 2; pass++) {
    if ((wr >> 1) == pass) {  // waves wr in {2*pass, 2*pass+1}
#pragma unroll
      for (int mt = 0; mt < 2; mt++)
#pragma unroll
        for (int nt = 0; nt < 2; nt++) {
          int cl = wc * 64 + nt * 32 + l31;
          int col = (int)tileN + cl;
          float sc = g2[col] * rsqrtf(v2[col] + EPS);
          float off = sc * (b2[col] - m2[col]) + be2[col];
          int rbase = (wr & 1) * 64 + mt * 32 + 4 * lh;
#pragma unroll
          for (int q = 0; q < 16; q++) {
            int rl = rbase + (q & 3) + 8 * (q >> 2);
            float zz = sc * (float)acc[mt][nt][q] + off;
            zz = fminf(1.f, fmaxf(-1.f, zz));
            zb[rl * 132 + cl] = zz;
          }
        }
    }
    __builtin_amdgcn_s_barrier();

#pragma unroll
    for (int i = 0; i < 3; i++) {
      int task = t + i * 512;  // 1280 tasks = 128 rows x 10 classes
      if (task < 1280) {
        int row = task / 10, cls = task - row * 10;
        float s = 0.f;
#pragma unroll
        for (int c4 = 0; c4 < 32; c4++) {
          float4 zv = *(const float4*)&zb[row * 132 + c4 * 4];
          float4 wv4 = *(const float4*)&w3s[cls * 132 + c4 * 4];
          s += zv.x * wv4.x + zv.y * wv4.y + zv.z * wv4.z + zv.w * wv4.w;
        }
        atomicAdd(&logits[(tileM + pass * 128 + row) * 10 + cls], s);
      }
    }
    __builtin_amdgcn_s_barrier();
  }
}

// ---------- +b3, log_softmax over logits[4096][10] -------------------------
__global__ __launch_bounds__(256) void lsm2(const float* __restrict__ logits,
                                            const float* __restrict__ b3,
                                            float* __restrict__ out) {
  int r = blockIdx.x * 256 + threadIdx.x;
  const float* lr = logits + r * 10;
  float v[10];
#pragma unroll
  for (int j = 0; j < 10; j++) v[j] = lr[j] + b3[j];
  float m = v[0];
#pragma unroll
  for (int j = 1; j < 10; j++) m = fmaxf(m, v[j]);
  float s = 0.f;
#pragma unroll
  for (int j = 0; j < 10; j++) s += expf(v[j] - m);
  float ls = logf(s);
#pragma unroll
  for (int j = 0; j < 10; j++) out[r * 10 + j] = v[j] - m - ls;
}

// ---------------------------------------------------------------------------
extern "C" void kernel_launch(void* const* d_in, const int* in_sizes, int n_in,
                              void* d_out, int out_size, void* d_ws, size_t ws_size,
                              hipStream_t stream) {
  const float* x   = (const float*)d_in[0];
  const float* W1  = (const float*)d_in[1];
  const float* b1  = (const float*)d_in[2];
  const float* g1  = (const float*)d_in[3];
  const float* be1 = (const float*)d_in[4];
  const float* m1  = (const float*)d_in[5];
  const float* v1  = (const float*)d_in[6];
  const float* W2  = (const float*)d_in[7];
  const float* b2  = (const float*)d_in[8];
  const float* g2  = (const float*)d_in[9];
  const float* be2 = (const float*)d_in[10];
  const float* m2  = (const float*)d_in[11];
  const float* v2  = (const float*)d_in[12];
  const float* W3  = (const float*)d_in[13];
  const float* b3  = (const float*)d_in[14];

  char* ws = (char*)d_ws;
  signed char* A8 = (signed char*)ws;                 // 4096*6272 = 25,690,112 B
  signed char* B8 = (signed char*)(ws + 25690112);    // 2048*6272 = 12,845,056 B
  float* logits = (float*)(ws + 38535168);            // 4096*10*4 = 163,840 B

  hipMemsetAsync(logits, 0, 4096 * 10 * sizeof(float), stream);
  stage1<<<4096 + 2048, 256, 0, stream>>>(x, W1, b1, g1, be1, m1, v1, W2, A8, B8);
  mm_i8<<<256, 512, 0, stream>>>(A8, B8, b2, g2, be2, m2, v2, W3, logits);
  lsm2<<<16, 256, 0, stream>>>(logits, b3, (float*)d_out);
}

// Round 9
// 99.908 us; speedup vs baseline: 1.5748x; 1.5748x over previous
//
#include <hip/hip_runtime.h>
#include <hip/hip_bf16.h>

// ---------------------------------------------------------------------------
// Binary CNN forward (eval):
//  conv3x3(sign(x), sign(W1)) + b1 -> maxpool2x2 -> BN -> hardtanh -> sign
//  -> (i8 MFMA GEMM vs sign(W2)) + b2 -> BN -> hardtanh
//  -> fused W3 projection (atomic partial sums) -> +b3, log_softmax
//
// All sign arithmetic is exact integer math (i8 dot products / i32 MFMA).
// mm_i8 (R9 = R6 geometry + counted-vmcnt pipeline):
//  128x128 tile, 4 waves (64x64 each, 2x2 of 32x32x32_i8), LDS double buffer
//  via global_load_lds with inverse-swizzled global source. Two barriers per
//  chunk; stage(kc+2) issued after barrier#2, s_waitcnt vmcnt(8) (counted,
//  never 0 mid-loop) before barrier#1 -> staging overlaps two chunks of
//  compute. Epilogue z stored as bf16 (stride 136) overlaying the buffers.
// ---------------------------------------------------------------------------

#define EPS 1e-5f

typedef int i32x4 __attribute__((ext_vector_type(4)));
typedef int i32x16 __attribute__((ext_vector_type(16)));

#define GLD_LDS(gsrc, ldst)                                                   \
  __builtin_amdgcn_global_load_lds(                                           \
      (const __attribute__((address_space(1))) void*)(gsrc),                  \
      (__attribute__((address_space(3))) void*)(ldst), 16, 0, 0)

// v_dot4_i32_i8: 4-way i8 dot + i32 acc in one instruction
#if defined(__has_builtin)
#if __has_builtin(__builtin_amdgcn_sdot4)
#define SDOT4(a, b, c) __builtin_amdgcn_sdot4((int)(a), (int)(b), (c), false)
#endif
#endif
#ifndef SDOT4
static __device__ __forceinline__ int sdot4_fb(int a, int b, int c) {
#pragma unroll
  for (int k = 0; k < 4; k++)
    c += ((int)(signed char)(a >> (8 * k))) * ((int)(signed char)(b >> (8 * k)));
  return c;
}
#define SDOT4(a, b, c) sdot4_fb((int)(a), (int)(b), (c))
#endif

// ---------- Stage 1 (merged): conv+pool+BN sign -> A8 | sign(W2) -> B8 ------
__global__ __launch_bounds__(256) void stage1(
    const float* __restrict__ x, const float* __restrict__ W1,
    const float* __restrict__ b1, const float* __restrict__ g1,
    const float* __restrict__ be1, const float* __restrict__ m1,
    const float* __restrict__ v1, const float* __restrict__ W2,
    signed char* __restrict__ A8, signed char* __restrict__ B8) {
  const int t = threadIdx.x;

  if (blockIdx.x >= 4096) {
    // ---- pack sign(W2) rows as int8: float4 loads, char4 stores ----
    const int row = blockIdx.x - 4096;
    const float4* wr4 = (const float4*)(W2 + (long)row * 6272);  // 1568 vec4
    signed char* br = B8 + (long)row * 6272;
#pragma unroll
    for (int it = 0; it < 7; it++) {
      int f4 = it * 256 + t;
      if (f4 < 1568) {
        float4 v = wr4[f4];
        char4 o;
        o.x = (v.x >= 0.f) ? 1 : -1;
        o.y = (v.y >= 0.f) ? 1 : -1;
        o.z = (v.z >= 0.f) ? 1 : -1;
        o.w = (v.w >= 0.f) ? 1 : -1;
        *(char4*)(br + f4 * 4) = o;
      }
    }
    return;
  }

  // ---- conv path ----
  __shared__ signed char sxb[30 * 32];  // padded binarized image, bytes
  __shared__ int wdw[32][3][2];         // weight dwords: [c][kh][dj]
  __shared__ float cAB[32][2];          // {cA, cB} per channel

  const int b = blockIdx.x;
  for (int i = t; i < 240; i += 256) ((int*)sxb)[i] = 0;  // zero incl. border
  __syncthreads();

  const float* xb = x + b * 784;
  for (int p = t; p < 784; p += 256) {
    float v = xb[p];
    sxb[(p / 28 + 1) * 32 + (p % 28) + 1] = (v >= 0.f) ? (signed char)1
                                                       : (signed char)-1;
  }
  if (t < 96) {
    int c = t / 3, kh = t - c * 3;
    const float* wp = W1 + c * 9 + kh * 3;
    unsigned u0 = (wp[0] >= 0.f) ? 0x01u : 0xFFu;
    unsigned u1 = (wp[1] >= 0.f) ? 0x01u : 0xFFu;
    unsigned u2 = (wp[2] >= 0.f) ? 0x01u : 0xFFu;
    wdw[c][kh][0] = (int)((u2 << 16) | (u1 << 8) | u0);   // (w0,w1,w2,0)
    wdw[c][kh][1] = (int)((u2 << 24) | (u1 << 16) | (u0 << 8));  // (0,w0,w1,w2)
  }
  if (t < 32) {
    float sc = g1[t] * rsqrtf(v1[t] + EPS);
    cAB[t][0] = sc;
    cAB[t][1] = sc * (b1[t] - m1[t]) + be1[t];  // pred = cA*maxconv + cB >= 0
  }
  __syncthreads();

  if (t < 196) {
    const int h = t / 14, w = t - h * 14;
    const int i0 = 2 * h, j0 = 2 * w;
    const int base = j0 & ~3, sh = (j0 & 3) * 8;  // sh in {0,16}
    unsigned prow[4];
#pragma unroll
    for (int ii = 0; ii < 4; ii++) {
      const int* rp = (const int*)&sxb[(i0 + ii) * 32 + base];
      unsigned long long chunk =
          (unsigned)rp[0] | ((unsigned long long)(unsigned)rp[1] << 32);
      prow[ii] = (unsigned)(chunk >> sh);  // bytes j0..j0+3 of padded row
    }
    signed char* ar = A8 + (long)b * 6272 + t;
#pragma unroll 8
    for (int c = 0; c < 32; c++) {
      int w00 = wdw[c][0][0], w01 = wdw[c][0][1];
      int w10 = wdw[c][1][0], w11 = wdw[c][1][1];
      int w20 = wdw[c][2][0], w21 = wdw[c][2][1];
      int c00 = SDOT4(prow[0], w00, SDOT4(prow[1], w10, SDOT4(prow[2], w20, 0)));
      int c01 = SDOT4(prow[0], w01, SDOT4(prow[1], w11, SDOT4(prow[2], w21, 0)));
      int c10 = SDOT4(prow[1], w00, SDOT4(prow[2], w10, SDOT4(prow[3], w20, 0)));
      int c11 = SDOT4(prow[1], w01, SDOT4(prow[2], w11, SDOT4(prow[3], w21, 0)));
      int mx = max(max(c00, c01), max(c10, c11));
      float pred = cAB[c][0] * (float)mx + cAB[c][1];
      ar[c * 196] = (pred >= 0.f) ? (signed char)1 : (signed char)-1;
    }
  }
}

// ---------- i8 MFMA GEMM 4096x2048 (K=6272) + BN2 + clip + W3 partials ------
#define TM 128
#define TN 128
#define BKB 128   // K bytes per chunk
#define NKC 49    // 6272 / 128

// LDS map:
//  [0,32768)     : buffer 0 (sA 16K | sB 16K)   (tiles: 128 rows x 128 B)
//  [32768,65536) : buffer 1
//  [0,34816)     : epilogue overlay zb[128][136] bf16 (after main loop)
//  [65536,70816) : w3s[10][132] f32
__global__ __launch_bounds__(256, 2) void mm_i8(
    const signed char* __restrict__ A8, const signed char* __restrict__ B8,
    const float* __restrict__ b2, const float* __restrict__ g2,
    const float* __restrict__ be2, const float* __restrict__ m2,
    const float* __restrict__ v2, const float* __restrict__ W3,
    float* __restrict__ logits) {
  __shared__ __align__(16) char smem[70816];
  float* w3s = (float*)(smem + 65536);

  const int t = threadIdx.x;
  const int lane = t & 63, wv = t >> 6;
  const int l31 = lane & 31, lh = lane >> 5;
  const int wr = wv >> 1, wc = wv & 1;   // 2x2 wave grid, 64x64 wave tile

  // XCD-aware block swizzle: 512 blocks, 8 XCDs -> each XCD gets 64
  // consecutive swz = 4 M-panels x 16 N-panels (A slice 3.2MB < 4MB L2).
  const int bid = blockIdx.x;
  const int swz = (bid & 7) * 64 + (bid >> 3);
  const long tileM = (long)(swz >> 4) * TM;
  const long tileN = (long)(swz & 15) * TN;

  for (int i = t; i < 1320; i += 256) {
    int cls = i / 132, c = i - cls * 132;
    w3s[i] = (c < 128) ? W3[cls * 2048 + tileN + c] : 0.f;
  }

  // Stage chunk kc into buffer buf: 8 gld_lds per wave (4 A + 4 B).
  // LDS linear (r, sl): off = r*128 + sl*16, holding global slot sl^(r&7)
  // (inverse-swizzled source; frag read applies the same XOR).
  auto stage = [&](int buf, int kc) {
    const int kb = kc * BKB;
    char* base = smem + buf * 32768;
#pragma unroll
    for (int i = 0; i < 4; i++) {
      int seg = wv * 4 + i;            // 16 segments x 1 KB = 16 KB
      int o = seg * 1024 + lane * 16;
      int r = o >> 7, sl = (o >> 4) & 7;
      int goff = kb + ((sl ^ (r & 7)) << 4);
      GLD_LDS(A8 + (tileM + r) * 6272 + goff, base + seg * 1024);
      GLD_LDS(B8 + (tileN + r) * 6272 + goff, base + 16384 + seg * 1024);
    }
  };

  i32x16 acc[2][2];
#pragma unroll
  for (int a = 0; a < 2; a++)
#pragma unroll
    for (int q = 0; q < 2; q++) acc[a][q] = (i32x16)0;

  // prologue: 2 chunks in flight
  stage(0, 0);
  stage(1, 1);

  for (int kc = 0; kc < NKC; kc++) {
    // counted wait: newest 8 outstanding = stage(kc+1); older (incl. kc) done.
    if (kc == NKC - 1)
      asm volatile("s_waitcnt vmcnt(0)" ::: "memory");
    else
      asm volatile("s_waitcnt vmcnt(8)" ::: "memory");
    __builtin_amdgcn_s_barrier();   // all waves' chunk-kc data landed

    const char* sAb = smem + (kc & 1) * 32768;
    const char* sBb = sAb + 16384;
#pragma unroll
    for (int ks = 0; ks < 4; ks++) {
      int slot = ks * 2 + lh;
      i32x4 af[2], bf[2];
#pragma unroll
      for (int mt = 0; mt < 2; mt++) {
        int r = wr * 64 + mt * 32 + l31;
        af[mt] = *(const i32x4*)(sAb + r * 128 + ((slot ^ (r & 7)) << 4));
      }
#pragma unroll
      for (int nt = 0; nt < 2; nt++) {
        int r = wc * 64 + nt * 32 + l31;
        bf[nt] = *(const i32x4*)(sBb + r * 128 + ((slot ^ (r & 7)) << 4));
      }
      __builtin_amdgcn_s_setprio(1);
#pragma unroll
      for (int mt = 0; mt < 2; mt++)
#pragma unroll
        for (int nt = 0; nt < 2; nt++)
          acc[mt][nt] = __builtin_amdgcn_mfma_i32_32x32x32_i8(
              af[mt], bf[nt], acc[mt][nt], 0, 0, 0);
      __builtin_amdgcn_s_setprio(0);
    }
    __builtin_amdgcn_s_barrier();   // all waves done reading buffer kc&1
    if (kc + 2 < NKC) stage(kc & 1, kc + 2);  // overwrite it; overlaps compute
  }

  // ---- epilogue: z = clip(BN2(dot)) as bf16 into LDS, then W3 partials -----
  unsigned short* zb = (unsigned short*)smem;  // [128][136] bf16 = 34816 B
#pragma unroll
  for (int mt = 0; mt < 2; mt++)
#pragma unroll
    for (int nt = 0; nt < 2; nt++) {
      int cl = wc * 64 + nt * 32 + l31;
      int col = (int)tileN + cl;
      float sc = g2[col] * rsqrtf(v2[col] + EPS);
      float off = sc * (b2[col] - m2[col]) + be2[col];
      int rbase = wr * 64 + mt * 32 + 4 * lh;
#pragma unroll
      for (int q = 0; q < 16; q++) {
        int rl = rbase + (q & 3) + 8 * (q >> 2);
        float zz = sc * (float)acc[mt][nt][q] + off;
        zz = fminf(1.f, fmaxf(-1.f, zz));
        __hip_bfloat16 hb = __float2bfloat16(zz);
        zb[rl * 136 + cl] = *(unsigned short*)&hb;
      }
    }
  __builtin_amdgcn_s_barrier();

#pragma unroll
  for (int i = 0; i < 5; i++) {
    int task = t + i * 256;           // 1280 tasks = 128 rows x 10 classes
    int row = task / 10, cls = task - row * 10;
    float s = 0.f;
#pragma unroll
    for (int c8 = 0; c8 < 16; c8++) {
      uint4 zB = *(const uint4*)(zb + row * 136 + c8 * 8);  // 8 bf16
      const float* wp = w3s + cls * 132 + c8 * 8;
      float4 w0 = *(const float4*)wp;
      float4 w1 = *(const float4*)(wp + 4);
      s += __uint_as_float(zB.x << 16) * w0.x +
           __uint_as_float(zB.x & 0xffff0000u) * w0.y +
           __uint_as_float(zB.y << 16) * w0.z +
           __uint_as_float(zB.y & 0xffff0000u) * w0.w;
      s += __uint_as_float(zB.z << 16) * w1.x +
           __uint_as_float(zB.z & 0xffff0000u) * w1.y +
           __uint_as_float(zB.w << 16) * w1.z +
           __uint_as_float(zB.w & 0xffff0000u) * w1.w;
    }
    atomicAdd(&logits[(tileM + row) * 10 + cls], s);
  }
}

// ---------- +b3, log_softmax over logits[4096][10] -------------------------
__global__ __launch_bounds__(256) void lsm2(const float* __restrict__ logits,
                                            const float* __restrict__ b3,
                                            float* __restrict__ out) {
  int r = blockIdx.x * 256 + threadIdx.x;
  const float* lr = logits + r * 10;
  float v[10];
#pragma unroll
  for (int j = 0; j < 10; j++) v[j] = lr[j] + b3[j];
  float m = v[0];
#pragma unroll
  for (int j = 1; j < 10; j++) m = fmaxf(m, v[j]);
  float s = 0.f;
#pragma unroll
  for (int j = 0; j < 10; j++) s += expf(v[j] - m);
  float ls = logf(s);
#pragma unroll
  for (int j = 0; j < 10; j++) out[r * 10 + j] = v[j] - m - ls;
}

// ---------------------------------------------------------------------------
extern "C" void kernel_launch(void* const* d_in, const int* in_sizes, int n_in,
                              void* d_out, int out_size, void* d_ws, size_t ws_size,
                              hipStream_t stream) {
  const float* x   = (const float*)d_in[0];
  const float* W1  = (const float*)d_in[1];
  const float* b1  = (const float*)d_in[2];
  const float* g1  = (const float*)d_in[3];
  const float* be1 = (const float*)d_in[4];
  const float* m1  = (const float*)d_in[5];
  const float* v1  = (const float*)d_in[6];
  const float* W2  = (const float*)d_in[7];
  const float* b2  = (const float*)d_in[8];
  const float* g2  = (const float*)d_in[9];
  const float* be2 = (const float*)d_in[10];
  const float* m2  = (const float*)d_in[11];
  const float* v2  = (const float*)d_in[12];
  const float* W3  = (const float*)d_in[13];
  const float* b3  = (const float*)d_in[14];

  char* ws = (char*)d_ws;
  signed char* A8 = (signed char*)ws;                 // 4096*6272 = 25,690,112 B
  signed char* B8 = (signed char*)(ws + 25690112);    // 2048*6272 = 12,845,056 B
  float* logits = (float*)(ws + 38535168);            // 4096*10*4 = 163,840 B

  hipMemsetAsync(logits, 0, 4096 * 10 * sizeof(float), stream);
  stage1<<<4096 + 2048, 256, 0, stream>>>(x, W1, b1, g1, be1, m1, v1, W2, A8, B8);
  mm_i8<<<512, 256, 0, stream>>>(A8, B8, b2, g2, be2, m2, v2, W3, logits);
  lsm2<<<16, 256, 0, stream>>>(logits, b3, (float*)d_out);
}